// Round 3
// baseline (396.668 us; speedup 1.0000x reference)
//
#include <hip/hip_runtime.h>

#define CN   62
#define CNP  64           // padded row stride for P/L LDS tiles (16B-aligned rows)
#define FIN  512
#define FOUT 256
#define KCH  5
#define JF   (CN*FIN)     // 31744
#define JF4  (JF/4)       // 7936
#define CC   (CN*CN)      // 3844

typedef float v4 __attribute__((ext_vector_type(4)));
typedef float v2 __attribute__((ext_vector_type(2)));

// ---------------------------------------------------------------------------
// Kernel 1 (merged): block 0 -> adjacency MLP + Laplacian + Chebyshev P_0..P_4
//                    blocks 1..160 -> S[k][c][n][f] = sum_fo chebW[k][f][fo]*fcw[c,fo,n]
// R3: S-blocks read f-rows (half-wave-broadcast) directly from global/L1
//     instead of LDS -> only the per-lane w-read stays on the LDS pipe
//     (320 -> 64 b128/thread); sF staging deleted.
// ---------------------------------------------------------------------------
__global__ __launch_bounds__(512) void k_pre(
    const float* __restrict__ coord, const float* __restrict__ w1,
    const float* __restrict__ b1, const float* __restrict__ w2,
    const float* __restrict__ b2, const float* __restrict__ chebW,
    const float* __restrict__ fcw, float* __restrict__ Pg,
    float* __restrict__ S2)
{
    __shared__ float smem[24704];    // 98.8 KB, aliased per role
    const int tid = threadIdx.x;
    const int bid = blockIdx.x;

    if (bid == 0) {
        // ---- setup: MLP adjacency -> threshold -> Laplacian -> P_k ----
        float* sL  = smem;            // [62][64]
        float* sB0 = smem + 3968;     // [62][64]
        float* sB1 = smem + 7936;
        float* sB2 = smem + 11904;
        float* sDis= smem + 15872;    // 62
        float* sWt = smem + 16000;    // [64][4] transposed w1
        float* sBW = smem + 16256;    // [64][2] packed (b1,w2)

        // stage MLP weights once
        if (tid < 64) {
            int u = tid;
            v4 w; w.x = w1[u]; w.y = w1[64+u]; w.z = w1[128+u]; w.w = w1[192+u];
            *(v4*)(sWt + 4*u) = w;
            v2 bw; bw.x = b1[u]; bw.y = w2[u];
            *(v2*)(sBW + 2*u) = bw;
        }
        __syncthreads();

        // phase 1: adjacency MLP + threshold. 8 edges/thread in registers,
        // u-outer so each (w,b) pair is read from LDS exactly once.
        float ec0[8], ec1[8], ec2[8], ec3[8], acc[8];
        const float bias2 = b2[0];
        #pragma unroll
        for (int p = 0; p < 8; ++p) {
            int e = tid + p*512;
            int ecl = (e < CC) ? e : (CC-1);
            v4 cv = *(const v4*)(coord + ecl*4);
            ec0[p] = cv.x; ec1[p] = cv.y; ec2[p] = cv.z; ec3[p] = cv.w;
            acc[p] = bias2;
        }
        for (int u = 0; u < 64; ++u) {
            v4 w  = *(const v4*)(sWt + 4*u);
            v2 bw = *(const v2*)(sBW + 2*u);
            #pragma unroll
            for (int p = 0; p < 8; ++p) {
                float h = bw.x + ec0[p]*w.x + ec1[p]*w.y + ec2[p]*w.z + ec3[p]*w.w;
                acc[p] += fmaxf(h, 0.0f) * bw.y;
            }
        }
        #pragma unroll
        for (int p = 0; p < 8; ++p) {
            int e = tid + p*512;
            if (e < CC) {
                int i = e / CN, j = e % CN;
                sL[i*CNP + j] = (acc[p] > 0.1f && i != j) ? acc[p] : 0.0f;
            }
        }
        // zero pads of all four [62][64] buffers
        for (int z = tid; z < 4*128; z += 512) {           // pad rows 62,63
            smem[(z >> 7)*3968 + 62*CNP + (z & 127)] = 0.f;
        }
        if (tid < 4*62) {                                  // pad cols 62,63
            int b = tid / CN, rr = tid % CN;
            float* p = smem + b*3968 + rr*CNP;
            p[62] = 0.f; p[63] = 0.f;
        }
        __syncthreads();

        // degrees (rotated j to avoid same-bank column walk)
        if (tid < CN) {
            float d = 0.f;
            for (int jj = 0; jj < CN; ++jj) {
                int j = jj + tid; if (j >= CN) j -= CN;
                d += sL[tid*CNP + j];
            }
            sDis[tid] = (d > 0.f) ? (1.0f / sqrtf(d)) : 0.f;
        }
        __syncthreads();

        // normalize -> L, init P0 = I, P1 = L
        for (int e = tid; e < CC; e += 512) {
            int i = e / CN, j = e % CN;
            float l = -(sDis[i] * sL[i*CNP + j] * sDis[j]);
            sL[i*CNP + j] = l;
            float id = (i == j) ? 1.f : 0.f;
            sB0[i*CNP + j] = id;
            sB1[i*CNP + j] = l;
            Pg[e]      = id;
            Pg[CC + e] = l;
        }
        __syncthreads();

        // phase 3: P_k = 2*L*P_{k-1} - P_{k-2}; L-row cached in registers.
        const int i  = tid >> 3;          // 0..63 (rows 62,63 idle)
        const int j0 = (tid & 7) * 8;     // 8-wide column group
        float Lr[CNP];
        if (i < CN) {
            #pragma unroll
            for (int m4 = 0; m4 < 16; ++m4) {
                v4 t = *(const v4*)(sL + i*CNP + m4*4);
                Lr[m4*4+0] = t.x; Lr[m4*4+1] = t.y;
                Lr[m4*4+2] = t.z; Lr[m4*4+3] = t.w;
            }
        }

        auto cheb_step = [&](const float* Pa, const float* Pb, float* Pc, int k) {
            if (i < CN) {
                v4 acc0 = {0.f,0.f,0.f,0.f}, acc1 = {0.f,0.f,0.f,0.f};
                #pragma unroll
                for (int m = 0; m < CNP; ++m) {   // pads contribute exact 0
                    float lm = Lr[m];
                    v4 p0 = *(const v4*)(Pb + m*CNP + j0);
                    v4 p1 = *(const v4*)(Pb + m*CNP + j0 + 4);
                    acc0 += lm * p0;
                    acc1 += lm * p1;
                }
                v4 pa0 = *(const v4*)(Pa + i*CNP + j0);
                v4 pa1 = *(const v4*)(Pa + i*CNP + j0 + 4);
                v4 r0 = 2.f*acc0 - pa0;
                v4 r1 = 2.f*acc1 - pa1;
                *(v4*)(Pc + i*CNP + j0)     = r0;
                *(v4*)(Pc + i*CNP + j0 + 4) = r1;
                float ov[8] = {r0.x,r0.y,r0.z,r0.w,r1.x,r1.y,r1.z,r1.w};
                float* pgk = Pg + (size_t)k*CC + i*CN + j0;
                #pragma unroll
                for (int t = 0; t < 8; ++t)
                    if (j0 + t < CN) pgk[t] = ov[t];
            }
            __syncthreads();
        };
        cheb_step(sB0, sB1, sB2, 2);
        cheb_step(sB1, sB2, sB0, 3);
        cheb_step(sB2, sB0, sB1, 4);
    } else {
        // ---- S: S2[((k*62+c)*2+n)*512+f] = sum_fo chebW[k][f][fo]*fcw[c*512+2*fo+n]
        // grid decode: 160 blocks = 5 k * 16 f-tiles(32) * 2 c-halves(31)
        int b  = bid - 1;
        int k  = b >> 5;
        int r  = b & 31;
        int f0 = (r >> 1) * 32;
        int ch = r & 1;

        float* sW = smem;           // [32][256] XOR-swizzled on 16B granules

        // stage chebW f-tile (v4, swizzled: granule g -> g ^ (row&7))
        v4* sW4 = (v4*)sW;
        const v4* cwb4 = (const v4*)(chebW + (size_t)(k*FIN + f0) * FOUT);
        for (int idx = tid; idx < 32*64; idx += 512) {
            int rr = idx >> 6, qg = idx & 63;
            sW4[rr*64 + (qg ^ (rr & 7))] = cwb4[idx];
        }
        __syncthreads();

        const int f_local = tid & 31;
        const int c_local = tid >> 5;                       // 0..15
        const int xr = f_local & 7;
        const int c0 = c_local;
        const int c1 = (c_local < 15) ? (c_local + 16) : 15; // clamp; dup discarded
        const v4* wr4   = (const v4*)sW + f_local*64;        // swizzled row
        // f-rows read straight from global: half-wave-broadcast addresses,
        // 62 KB working set -> L1/L2-resident; keeps the LDS pipe for w only.
        const v4* frow0 = (const v4*)(fcw + (size_t)(ch*31 + c0) * 512);
        const v4* frow1 = (const v4*)(fcw + (size_t)(ch*31 + c1) * 512);

        float a00 = 0.f, a01 = 0.f, a10 = 0.f, a11 = 0.f;
        #pragma unroll 4
        for (int q = 0; q < 64; ++q) {        // 4 fo per iteration
            v4 w4  = wr4[q ^ xr];
            v4 f00 = frow0[2*q], f01 = frow0[2*q + 1];
            v4 f10 = frow1[2*q], f11 = frow1[2*q + 1];
            a00 += w4.x*f00.x + w4.y*f00.z + w4.z*f01.x + w4.w*f01.z;
            a01 += w4.x*f00.y + w4.y*f00.w + w4.z*f01.y + w4.w*f01.w;
            a10 += w4.x*f10.x + w4.y*f10.z + w4.z*f11.x + w4.w*f11.z;
            a11 += w4.x*f10.y + w4.y*f10.w + w4.z*f11.y + w4.w*f11.w;
        }
        size_t base0 = ((size_t)((k*62 + ch*31 + c0)*2))*512 + f0 + f_local;
        S2[base0]       = a00;   // n=0
        S2[base0 + 512] = a01;   // n=1
        if (c_local < 15) {
            size_t base1 = ((size_t)((k*62 + ch*31 + c_local + 16)*2))*512 + f0 + f_local;
            S2[base1]       = a10;
            S2[base1 + 512] = a11;
        }
    }
}

// ---------------------------------------------------------------------------
// Kernel 2: blocks 0..123 -> G[n][j*512+f] = cw * sum_{k,c} P_k[c,j]*S2[k,c,n,f]
//           block 124     -> const[n] (independent of everything above)
// ---------------------------------------------------------------------------
__global__ __launch_bounds__(256) void k_G3(
    const float* __restrict__ Pg, const float* __restrict__ S2,
    const float* __restrict__ chebb, const float* __restrict__ convw,
    const float* __restrict__ convb, const float* __restrict__ fcw,
    const float* __restrict__ fcb, float* __restrict__ G,
    float* __restrict__ constv)
{
    const int tid = threadIdx.x;
    const int bid = blockIdx.x;
    __shared__ float sP[310];
    __shared__ float sp4[4];

    if (bid < 124) {
        int n = bid / CN, j = bid % CN;
        for (int i = tid; i < 310; i += 256) {
            int k = i / CN, c = i % CN;
            sP[i] = Pg[k*CC + c*CN + j];
        }
        __syncthreads();

        const v2* s2 = (const v2*)S2;
        float a0 = 0.f, a1 = 0.f;
        #pragma unroll 5
        for (int i = 0; i < 310; ++i) {
            float p = sP[i];
            v2 v = s2[(size_t)(i*2 + n)*256 + tid];
            a0 += p * v.x;
            a1 += p * v.y;
        }
        float cw = convw[0];
        v2 res; res.x = cw*a0; res.y = cw*a1;
        ((v2*)(G + (size_t)n*JF + j*512))[tid] = res;
    } else {
        // const[n] = sum_{c,fo} (cw*chebb[fo] + cb)*fcw[(c*256+fo)*2+n] + fcb[n]
        int w = tid >> 6, lane = tid & 63;
        int n = w & 1, half = w >> 1;
        float cw = convw[0], cb = convb[0];
        float acc = 0.f;
        for (int idx = lane + 64*half; idx < CN*FOUT; idx += 128) {
            int fo = idx & 255;
            acc += (cw * chebb[fo] + cb) * fcw[idx*2 + n];
        }
        for (int o = 32; o > 0; o >>= 1) acc += __shfl_down(acc, o, 64);
        if (lane == 0) sp4[w] = acc;
        __syncthreads();
        if (tid < 2) constv[tid] = sp4[tid] + sp4[tid + 2] + fcb[tid];
    }
}

// ---------------------------------------------------------------------------
// Kernel 3 (main, HBM-bound): out[b,n] = sum_jf x[b,jf]*G[n][jf] + const[n]
// R3: grid 1024, 2 batch rows/block -> 16 waves/CU (was 8) for deeper
//     outstanding-load queue on the x stream. Per-row loop order unchanged.
// ---------------------------------------------------------------------------
__global__ __launch_bounds__(256) void k_main(
    const float* __restrict__ x, const float* __restrict__ G,
    const float* __restrict__ constv, float* __restrict__ out)
{
    const int tid = threadIdx.x;
    const int b0  = blockIdx.x * 2;
    const v4* g0 = (const v4*)(G);
    const v4* g1 = (const v4*)(G + JF);
    const v4* x0 = (const v4*)(x + (size_t)b0 * JF);

    float a00=0, a01=0, a10=0, a11=0;

    #pragma unroll 4
    for (int i = tid; i < JF4; i += 256) {
        v4 gg0 = g0[i];
        v4 gg1 = g1[i];
        v4 x0v = __builtin_nontemporal_load(&x0[i]);
        v4 x1v = __builtin_nontemporal_load(&x0[JF4 + i]);
        a00 += x0v.x*gg0.x + x0v.y*gg0.y + x0v.z*gg0.z + x0v.w*gg0.w;
        a01 += x0v.x*gg1.x + x0v.y*gg1.y + x0v.z*gg1.z + x0v.w*gg1.w;
        a10 += x1v.x*gg0.x + x1v.y*gg0.y + x1v.z*gg0.z + x1v.w*gg0.w;
        a11 += x1v.x*gg1.x + x1v.y*gg1.y + x1v.z*gg1.z + x1v.w*gg1.w;
    }

    float vals[4] = { a00, a01, a10, a11 };
    for (int o = 32; o > 0; o >>= 1) {
        #pragma unroll
        for (int q = 0; q < 4; ++q) vals[q] += __shfl_down(vals[q], o, 64);
    }

    __shared__ float sred[4][4];
    int wave = tid >> 6, lane = tid & 63;
    if (lane == 0) {
        #pragma unroll
        for (int q = 0; q < 4; ++q) sred[wave][q] = vals[q];
    }
    __syncthreads();
    if (tid < 4) {
        float s = sred[0][tid] + sred[1][tid] + sred[2][tid] + sred[3][tid];
        int r = tid >> 1, n = tid & 1;
        out[(b0 + r)*2 + n] = s + constv[n];
    }
}

// ---------------------------------------------------------------------------
extern "C" void kernel_launch(void* const* d_in, const int* in_sizes, int n_in,
                              void* d_out, int out_size, void* d_ws, size_t ws_size,
                              hipStream_t stream)
{
    const float* x     = (const float*)d_in[0];
    const float* coord = (const float*)d_in[1];
    const float* aw1   = (const float*)d_in[2];
    const float* ab1   = (const float*)d_in[3];
    const float* aw2   = (const float*)d_in[4];
    const float* ab2   = (const float*)d_in[5];
    const float* chebW = (const float*)d_in[6];
    const float* chebb = (const float*)d_in[7];
    const float* convw = (const float*)d_in[8];
    const float* convb = (const float*)d_in[9];
    const float* fcw   = (const float*)d_in[10];
    const float* fcb   = (const float*)d_in[11];
    float* out = (float*)d_out;

    float* ws = (float*)d_ws;
    float* Pg = ws;                         // 5*3844           = 19220
    float* S2 = Pg + KCH*CC;                // 5*62*2*512       = 317440
    float* G  = S2 + KCH*CN*2*FIN;          // 2*31744          = 63488
    float* cv = G + 2*JF;                   // 2

    k_pre <<<161, 512, 0, stream>>>(coord, aw1, ab1, aw2, ab2, chebW, fcw, Pg, S2);
    k_G3  <<<125, 256, 0, stream>>>(Pg, S2, chebb, convw, convb, fcw, fcb, G, cv);
    k_main<<<1024, 256, 0, stream>>>(x, G, cv, out);
}

// Round 4
// 392.121 us; speedup vs baseline: 1.0116x; 1.0116x over previous
//
#include <hip/hip_runtime.h>

#define CN   62
#define CNP  64           // padded row stride for P/L LDS tiles (16B-aligned rows)
#define FIN  512
#define FOUT 256
#define KCH  5
#define JF   (CN*FIN)     // 31744
#define JF4  (JF/4)       // 7936
#define CC   (CN*CN)      // 3844

typedef float v4 __attribute__((ext_vector_type(4)));
typedef float v2 __attribute__((ext_vector_type(2)));

// ---------------------------------------------------------------------------
// Kernel 1 (merged): block 0 -> adjacency MLP + Laplacian + Chebyshev P_0..P_4
//                    blocks 1..160 -> S[k][c][n][f] = sum_fo chebW[k][f][fo]*fcw[c,fo,n]
// R4 = revert to R2 (best measured 392.4 us): LDS-staged sF + sW XOR-swizzle;
// k_main 4 rows/block, grid 512. R3's global-f-row + 2-row-split both
// regressed (BW-saturated, not latency-limited).
// ---------------------------------------------------------------------------
__global__ __launch_bounds__(512) void k_pre(
    const float* __restrict__ coord, const float* __restrict__ w1,
    const float* __restrict__ b1, const float* __restrict__ w2,
    const float* __restrict__ b2, const float* __restrict__ chebW,
    const float* __restrict__ fcw, float* __restrict__ Pg,
    float* __restrict__ S2)
{
    __shared__ float smem[24704];    // 98.8 KB, aliased per role
    const int tid = threadIdx.x;
    const int bid = blockIdx.x;

    if (bid == 0) {
        // ---- setup: MLP adjacency -> threshold -> Laplacian -> P_k ----
        float* sL  = smem;            // [62][64]
        float* sB0 = smem + 3968;     // [62][64]
        float* sB1 = smem + 7936;
        float* sB2 = smem + 11904;
        float* sDis= smem + 15872;    // 62
        float* sWt = smem + 16000;    // [64][4] transposed w1
        float* sBW = smem + 16256;    // [64][2] packed (b1,w2)

        // stage MLP weights once
        if (tid < 64) {
            int u = tid;
            v4 w; w.x = w1[u]; w.y = w1[64+u]; w.z = w1[128+u]; w.w = w1[192+u];
            *(v4*)(sWt + 4*u) = w;
            v2 bw; bw.x = b1[u]; bw.y = w2[u];
            *(v2*)(sBW + 2*u) = bw;
        }
        __syncthreads();

        // phase 1: adjacency MLP + threshold. 8 edges/thread in registers,
        // u-outer so each (w,b) pair is read from LDS exactly once.
        float ec0[8], ec1[8], ec2[8], ec3[8], acc[8];
        const float bias2 = b2[0];
        #pragma unroll
        for (int p = 0; p < 8; ++p) {
            int e = tid + p*512;
            int ecl = (e < CC) ? e : (CC-1);
            v4 cv = *(const v4*)(coord + ecl*4);
            ec0[p] = cv.x; ec1[p] = cv.y; ec2[p] = cv.z; ec3[p] = cv.w;
            acc[p] = bias2;
        }
        for (int u = 0; u < 64; ++u) {
            v4 w  = *(const v4*)(sWt + 4*u);
            v2 bw = *(const v2*)(sBW + 2*u);
            #pragma unroll
            for (int p = 0; p < 8; ++p) {
                float h = bw.x + ec0[p]*w.x + ec1[p]*w.y + ec2[p]*w.z + ec3[p]*w.w;
                acc[p] += fmaxf(h, 0.0f) * bw.y;
            }
        }
        #pragma unroll
        for (int p = 0; p < 8; ++p) {
            int e = tid + p*512;
            if (e < CC) {
                int i = e / CN, j = e % CN;
                sL[i*CNP + j] = (acc[p] > 0.1f && i != j) ? acc[p] : 0.0f;
            }
        }
        // zero pads of all four [62][64] buffers
        for (int z = tid; z < 4*128; z += 512) {           // pad rows 62,63
            smem[(z >> 7)*3968 + 62*CNP + (z & 127)] = 0.f;
        }
        if (tid < 4*62) {                                  // pad cols 62,63
            int b = tid / CN, rr = tid % CN;
            float* p = smem + b*3968 + rr*CNP;
            p[62] = 0.f; p[63] = 0.f;
        }
        __syncthreads();

        // degrees (rotated j to avoid same-bank column walk)
        if (tid < CN) {
            float d = 0.f;
            for (int jj = 0; jj < CN; ++jj) {
                int j = jj + tid; if (j >= CN) j -= CN;
                d += sL[tid*CNP + j];
            }
            sDis[tid] = (d > 0.f) ? (1.0f / sqrtf(d)) : 0.f;
        }
        __syncthreads();

        // normalize -> L, init P0 = I, P1 = L
        for (int e = tid; e < CC; e += 512) {
            int i = e / CN, j = e % CN;
            float l = -(sDis[i] * sL[i*CNP + j] * sDis[j]);
            sL[i*CNP + j] = l;
            float id = (i == j) ? 1.f : 0.f;
            sB0[i*CNP + j] = id;
            sB1[i*CNP + j] = l;
            Pg[e]      = id;
            Pg[CC + e] = l;
        }
        __syncthreads();

        // phase 3: P_k = 2*L*P_{k-1} - P_{k-2}; L-row cached in registers.
        const int i  = tid >> 3;          // 0..63 (rows 62,63 idle)
        const int j0 = (tid & 7) * 8;     // 8-wide column group
        float Lr[CNP];
        if (i < CN) {
            #pragma unroll
            for (int m4 = 0; m4 < 16; ++m4) {
                v4 t = *(const v4*)(sL + i*CNP + m4*4);
                Lr[m4*4+0] = t.x; Lr[m4*4+1] = t.y;
                Lr[m4*4+2] = t.z; Lr[m4*4+3] = t.w;
            }
        }

        auto cheb_step = [&](const float* Pa, const float* Pb, float* Pc, int k) {
            if (i < CN) {
                v4 acc0 = {0.f,0.f,0.f,0.f}, acc1 = {0.f,0.f,0.f,0.f};
                #pragma unroll
                for (int m = 0; m < CNP; ++m) {   // pads contribute exact 0
                    float lm = Lr[m];
                    v4 p0 = *(const v4*)(Pb + m*CNP + j0);
                    v4 p1 = *(const v4*)(Pb + m*CNP + j0 + 4);
                    acc0 += lm * p0;
                    acc1 += lm * p1;
                }
                v4 pa0 = *(const v4*)(Pa + i*CNP + j0);
                v4 pa1 = *(const v4*)(Pa + i*CNP + j0 + 4);
                v4 r0 = 2.f*acc0 - pa0;
                v4 r1 = 2.f*acc1 - pa1;
                *(v4*)(Pc + i*CNP + j0)     = r0;
                *(v4*)(Pc + i*CNP + j0 + 4) = r1;
                float ov[8] = {r0.x,r0.y,r0.z,r0.w,r1.x,r1.y,r1.z,r1.w};
                float* pgk = Pg + (size_t)k*CC + i*CN + j0;
                #pragma unroll
                for (int t = 0; t < 8; ++t)
                    if (j0 + t < CN) pgk[t] = ov[t];
            }
            __syncthreads();
        };
        cheb_step(sB0, sB1, sB2, 2);
        cheb_step(sB1, sB2, sB0, 3);
        cheb_step(sB2, sB0, sB1, 4);
    } else {
        // ---- S: S2[((k*62+c)*2+n)*512+f] = sum_fo chebW[k][f][fo]*fcw[c*512+2*fo+n]
        // grid decode: 160 blocks = 5 k * 16 f-tiles(32) * 2 c-halves(31)
        int b  = bid - 1;
        int k  = b >> 5;
        int r  = b & 31;
        int f0 = (r >> 1) * 32;
        int ch = r & 1;

        float* sW = smem;           // [32][256] XOR-swizzled on 16B granules
        float* sF = smem + 8192;    // [31][512] = 15872 floats

        // stage chebW f-tile (v4, swizzled: granule g -> g ^ (row&7))
        v4* sW4 = (v4*)sW;
        const v4* cwb4 = (const v4*)(chebW + (size_t)(k*FIN + f0) * FOUT);
        for (int idx = tid; idx < 32*64; idx += 512) {
            int rr = idx >> 6, qg = idx & 63;
            sW4[rr*64 + (qg ^ (rr & 7))] = cwb4[idx];
        }
        // stage fcw c-half (v4; rows are contiguous 512 floats)
        v4* sF4 = (v4*)sF;
        const v4* fb4 = (const v4*)(fcw + (size_t)(ch*31) * 512);
        for (int idx = tid; idx < 31*128; idx += 512) sF4[idx] = fb4[idx];
        __syncthreads();

        const int f_local = tid & 31;
        const int c_local = tid >> 5;                       // 0..15
        const int xr = f_local & 7;
        const int c0 = c_local;
        const int c1 = (c_local < 15) ? (c_local + 16) : 15; // clamp; dup discarded
        const v4* wr4   = (const v4*)sW + f_local*64;        // swizzled row
        const v4* frow0 = (const v4*)(sF + c0*512);          // broadcast across 32 lanes
        const v4* frow1 = (const v4*)(sF + c1*512);

        float a00 = 0.f, a01 = 0.f, a10 = 0.f, a11 = 0.f;
        #pragma unroll 4
        for (int q = 0; q < 64; ++q) {        // 4 fo per iteration
            v4 w4  = wr4[q ^ xr];
            v4 f00 = frow0[2*q], f01 = frow0[2*q + 1];
            v4 f10 = frow1[2*q], f11 = frow1[2*q + 1];
            a00 += w4.x*f00.x + w4.y*f00.z + w4.z*f01.x + w4.w*f01.z;
            a01 += w4.x*f00.y + w4.y*f00.w + w4.z*f01.y + w4.w*f01.w;
            a10 += w4.x*f10.x + w4.y*f10.z + w4.z*f11.x + w4.w*f11.z;
            a11 += w4.x*f10.y + w4.y*f10.w + w4.z*f11.y + w4.w*f11.w;
        }
        size_t base0 = ((size_t)((k*62 + ch*31 + c0)*2))*512 + f0 + f_local;
        S2[base0]       = a00;   // n=0
        S2[base0 + 512] = a01;   // n=1
        if (c_local < 15) {
            size_t base1 = ((size_t)((k*62 + ch*31 + c_local + 16)*2))*512 + f0 + f_local;
            S2[base1]       = a10;
            S2[base1 + 512] = a11;
        }
    }
}

// ---------------------------------------------------------------------------
// Kernel 2: blocks 0..123 -> G[n][j*512+f] = cw * sum_{k,c} P_k[c,j]*S2[k,c,n,f]
//           block 124     -> const[n] (independent of everything above)
// ---------------------------------------------------------------------------
__global__ __launch_bounds__(256) void k_G3(
    const float* __restrict__ Pg, const float* __restrict__ S2,
    const float* __restrict__ chebb, const float* __restrict__ convw,
    const float* __restrict__ convb, const float* __restrict__ fcw,
    const float* __restrict__ fcb, float* __restrict__ G,
    float* __restrict__ constv)
{
    const int tid = threadIdx.x;
    const int bid = blockIdx.x;
    __shared__ float sP[310];
    __shared__ float sp4[4];

    if (bid < 124) {
        int n = bid / CN, j = bid % CN;
        for (int i = tid; i < 310; i += 256) {
            int k = i / CN, c = i % CN;
            sP[i] = Pg[k*CC + c*CN + j];
        }
        __syncthreads();

        const v2* s2 = (const v2*)S2;
        float a0 = 0.f, a1 = 0.f;
        #pragma unroll 5
        for (int i = 0; i < 310; ++i) {
            float p = sP[i];
            v2 v = s2[(size_t)(i*2 + n)*256 + tid];
            a0 += p * v.x;
            a1 += p * v.y;
        }
        float cw = convw[0];
        v2 res; res.x = cw*a0; res.y = cw*a1;
        ((v2*)(G + (size_t)n*JF + j*512))[tid] = res;
    } else {
        // const[n] = sum_{c,fo} (cw*chebb[fo] + cb)*fcw[(c*256+fo)*2+n] + fcb[n]
        int w = tid >> 6, lane = tid & 63;
        int n = w & 1, half = w >> 1;
        float cw = convw[0], cb = convb[0];
        float acc = 0.f;
        for (int idx = lane + 64*half; idx < CN*FOUT; idx += 128) {
            int fo = idx & 255;
            acc += (cw * chebb[fo] + cb) * fcw[idx*2 + n];
        }
        for (int o = 32; o > 0; o >>= 1) acc += __shfl_down(acc, o, 64);
        if (lane == 0) sp4[w] = acc;
        __syncthreads();
        if (tid < 2) constv[tid] = sp4[tid] + sp4[tid + 2] + fcb[tid];
    }
}

// ---------------------------------------------------------------------------
// Kernel 3 (main, HBM-bound): out[b,n] = sum_jf x[b,jf]*G[n][jf] + const[n]
// 4 batch rows/block, grid 512 (R2 config — best measured).
// ---------------------------------------------------------------------------
__global__ __launch_bounds__(256) void k_main(
    const float* __restrict__ x, const float* __restrict__ G,
    const float* __restrict__ constv, float* __restrict__ out)
{
    const int tid = threadIdx.x;
    const int b0  = blockIdx.x * 4;
    const v4* g0 = (const v4*)(G);
    const v4* g1 = (const v4*)(G + JF);
    const v4* x0 = (const v4*)(x + (size_t)b0 * JF);

    float a00=0, a01=0, a10=0, a11=0, a20=0, a21=0, a30=0, a31=0;

    #pragma unroll 4
    for (int i = tid; i < JF4; i += 256) {
        v4 gg0 = g0[i];
        v4 gg1 = g1[i];
        v4 x0v = __builtin_nontemporal_load(&x0[i]);
        v4 x1v = __builtin_nontemporal_load(&x0[JF4 + i]);
        v4 x2v = __builtin_nontemporal_load(&x0[2*JF4 + i]);
        v4 x3v = __builtin_nontemporal_load(&x0[3*JF4 + i]);
        a00 += x0v.x*gg0.x + x0v.y*gg0.y + x0v.z*gg0.z + x0v.w*gg0.w;
        a01 += x0v.x*gg1.x + x0v.y*gg1.y + x0v.z*gg1.z + x0v.w*gg1.w;
        a10 += x1v.x*gg0.x + x1v.y*gg0.y + x1v.z*gg0.z + x1v.w*gg0.w;
        a11 += x1v.x*gg1.x + x1v.y*gg1.y + x1v.z*gg1.z + x1v.w*gg1.w;
        a20 += x2v.x*gg0.x + x2v.y*gg0.y + x2v.z*gg0.z + x2v.w*gg0.w;
        a21 += x2v.x*gg1.x + x2v.y*gg1.y + x2v.z*gg1.z + x2v.w*gg1.w;
        a30 += x3v.x*gg0.x + x3v.y*gg0.y + x3v.z*gg0.z + x3v.w*gg0.w;
        a31 += x3v.x*gg1.x + x3v.y*gg1.y + x3v.z*gg1.z + x3v.w*gg1.w;
    }

    float vals[8] = { a00, a01, a10, a11, a20, a21, a30, a31 };
    for (int o = 32; o > 0; o >>= 1) {
        #pragma unroll
        for (int q = 0; q < 8; ++q) vals[q] += __shfl_down(vals[q], o, 64);
    }

    __shared__ float sred[4][8];
    int wave = tid >> 6, lane = tid & 63;
    if (lane == 0) {
        #pragma unroll
        for (int q = 0; q < 8; ++q) sred[wave][q] = vals[q];
    }
    __syncthreads();
    if (tid < 8) {
        float s = sred[0][tid] + sred[1][tid] + sred[2][tid] + sred[3][tid];
        int r = tid >> 1, n = tid & 1;
        out[(b0 + r)*2 + n] = s + constv[n];
    }
}

// ---------------------------------------------------------------------------
extern "C" void kernel_launch(void* const* d_in, const int* in_sizes, int n_in,
                              void* d_out, int out_size, void* d_ws, size_t ws_size,
                              hipStream_t stream)
{
    const float* x     = (const float*)d_in[0];
    const float* coord = (const float*)d_in[1];
    const float* aw1   = (const float*)d_in[2];
    const float* ab1   = (const float*)d_in[3];
    const float* aw2   = (const float*)d_in[4];
    const float* ab2   = (const float*)d_in[5];
    const float* chebW = (const float*)d_in[6];
    const float* chebb = (const float*)d_in[7];
    const float* convw = (const float*)d_in[8];
    const float* convb = (const float*)d_in[9];
    const float* fcw   = (const float*)d_in[10];
    const float* fcb   = (const float*)d_in[11];
    float* out = (float*)d_out;

    float* ws = (float*)d_ws;
    float* Pg = ws;                         // 5*3844           = 19220
    float* S2 = Pg + KCH*CC;                // 5*62*2*512       = 317440
    float* G  = S2 + KCH*CN*2*FIN;          // 2*31744          = 63488
    float* cv = G + 2*JF;                   // 2

    k_pre <<<161, 512, 0, stream>>>(coord, aw1, ab1, aw2, ab2, chebW, fcw, Pg, S2);
    k_G3  <<<125, 256, 0, stream>>>(Pg, S2, chebb, convw, convb, fcw, fcb, G, cv);
    k_main<<<512, 256, 0, stream>>>(x, G, cv, out);
}